// Round 3
// baseline (495.771 us; speedup 1.0000x reference)
//
#include <hip/hip_runtime.h>
#include <hip/hip_bf16.h>

// B=2, S=768, H=768, NH=12, D=64, NKEY=9216. Output fp32 [B][S][NH][D].
// Round 3: flash kernel with NO LDS staging (direct global B-fragments, no
// barriers), fixed-shift softmax (no online max/rescale), lane-local l sum.
// 64x64 GEMM tiles for 4x block parallelism. MFMA: v_mfma_f32_16x16x32_bf16.

typedef __bf16 bf16_t;
typedef __bf16 bf16x8 __attribute__((ext_vector_type(8)));
typedef float f32x4 __attribute__((ext_vector_type(4)));

#define MFMA16(a, b, c) __builtin_amdgcn_mfma_f32_16x16x32_bf16((a), (b), (c), 0, 0, 0)
#define LOG2E 1.44269504088896340736f
#define SCALE_Q 0.18033688011112042f /* (1/8) * log2(e) */
#define SHIFT_C 8.0f                 /* fixed softmax shift (base-2 units) */
#define NSPLIT 8
#define KCHUNK 1152 /* 9216/8, 18 iters of 64 */

// ---------------- transpose + convert: Wt[n][k] = (bf16)W[k][n], 768x768 ----
__global__ __launch_bounds__(256) void transpose_cvt3(const float* __restrict__ Wq,
                                                      const float* __restrict__ Wk,
                                                      const float* __restrict__ Wv,
                                                      bf16_t* __restrict__ Wt) {
  __shared__ float t[32][33];
  const float* W = (blockIdx.z == 0) ? Wq : (blockIdx.z == 1) ? Wk : Wv;
  bf16_t* o = Wt + (size_t)blockIdx.z * 589824;
  const int bx = blockIdx.x * 32;
  const int by = blockIdx.y * 32;
  const int tx = threadIdx.x, ty = threadIdx.y;
#pragma unroll
  for (int i = 0; i < 32; i += 8) t[ty + i][tx] = W[(bx + ty + i) * 768 + by + tx];
  __syncthreads();
#pragma unroll
  for (int i = 0; i < 32; i += 8)
    o[(by + ty + i) * 768 + bx + tx] = (bf16_t)t[tx][ty + i];
}

// ---------------- canonical C[M][N] = A[M][K] * B[N][K]^T, bf16 MFMA --------
__device__ __forceinline__ bf16x8 cvt8(const float* __restrict__ src) {
  const float4 a = *(const float4*)src;
  const float4 b = *(const float4*)(src + 4);
  bf16x8 o;
  o[0] = (bf16_t)a.x; o[1] = (bf16_t)a.y; o[2] = (bf16_t)a.z; o[3] = (bf16_t)a.w;
  o[4] = (bf16_t)b.x; o[5] = (bf16_t)b.y; o[6] = (bf16_t)b.z; o[7] = (bf16_t)b.w;
  return o;
}

template <int BM, int BN, bool AF32, bool BF32, typename EPI>
__device__ __forceinline__ void gemm_core(char* __restrict__ smem,
                                          const void* __restrict__ Ap, int lda,
                                          const void* __restrict__ Bp, int ldb,
                                          int K, int m0, int n0, EPI epi) {
  constexpr int MT = BM / 32;
  constexpr int NT = BN / 32;
  constexpr int ACH = BM * 8;
  constexpr int BCH = BN * 8;
  char* sA = smem;
  char* sB = smem + BM * 144;

  const int tid = threadIdx.x;
  const int lane = tid & 63;
  const int w = tid >> 6;
  const int l15 = lane & 15, quad = lane >> 4;
  const int wm = (w & 1) * (BM / 2);
  const int wn = (w >> 1) * (BN / 2);

  const f32x4 fzero = {0.f, 0.f, 0.f, 0.f};
  f32x4 acc[MT][NT];
#pragma unroll
  for (int i = 0; i < MT; ++i)
#pragma unroll
    for (int j = 0; j < NT; ++j) acc[i][j] = fzero;

  for (int kk = 0; kk < K; kk += 64) {
#pragma unroll
    for (int c = tid; c < ACH; c += 256) {
      const int r = c >> 3, ch = c & 7;
      if constexpr (AF32) {
        const float* s = (const float*)Ap + (size_t)(m0 + r) * lda + kk + ch * 8;
        *(bf16x8*)(sA + r * 144 + ch * 16) = cvt8(s);
      } else {
        const bf16_t* s = (const bf16_t*)Ap + (size_t)(m0 + r) * lda + kk + ch * 8;
        *(uint4*)(sA + r * 144 + ch * 16) = *(const uint4*)s;
      }
    }
#pragma unroll
    for (int c = tid; c < BCH; c += 256) {
      const int r = c >> 3, ch = c & 7;
      if constexpr (BF32) {
        const float* s = (const float*)Bp + (size_t)(n0 + r) * ldb + kk + ch * 8;
        *(bf16x8*)(sB + r * 144 + ch * 16) = cvt8(s);
      } else {
        const bf16_t* s = (const bf16_t*)Bp + (size_t)(n0 + r) * ldb + kk + ch * 8;
        *(uint4*)(sB + r * 144 + ch * 16) = *(const uint4*)s;
      }
    }
    __syncthreads();
#pragma unroll
    for (int ks = 0; ks < 2; ++ks) {
      bf16x8 af[MT], bfr[NT];
#pragma unroll
      for (int i = 0; i < MT; ++i)
        af[i] = *(const bf16x8*)(sA + (wm + i * 16 + l15) * 144 + ks * 64 + quad * 16);
#pragma unroll
      for (int j = 0; j < NT; ++j)
        bfr[j] = *(const bf16x8*)(sB + (wn + j * 16 + l15) * 144 + ks * 64 + quad * 16);
#pragma unroll
      for (int i = 0; i < MT; ++i)
#pragma unroll
        for (int j = 0; j < NT; ++j) acc[i][j] = MFMA16(af[i], bfr[j], acc[i][j]);
    }
    __syncthreads();
  }
#pragma unroll
  for (int i = 0; i < MT; ++i)
#pragma unroll
    for (int j = 0; j < NT; ++j)
#pragma unroll
      for (int p = 0; p < 4; ++p)
        epi(m0 + wm + i * 16 + quad * 4 + p, n0 + wn + j * 16 + l15, acc[i][j][p]);
}

// Merged QKV projections (64x64 tiles).
//  y<12 : q[b,h,s,d] = (hid @ Wq + bq) * SCALE_Q              (bf16 out)
//  y>=12: ktvt[(h,d)][(b,s)] rows 0..767 k^T(+bk), 768..1535 v^T(+bv)
__global__ __launch_bounds__(256) void gemm_qkv(const float* __restrict__ hid,
                                                const bf16_t* __restrict__ wT,
                                                const float* __restrict__ bq,
                                                const float* __restrict__ bk,
                                                const float* __restrict__ bv,
                                                bf16_t* __restrict__ q,
                                                bf16_t* __restrict__ ktvt) {
  __shared__ __align__(16) char smem[(64 + 64) * 144];
  if (blockIdx.y < 12) {
    const int m0 = blockIdx.x * 64, n0 = blockIdx.y * 64;
    auto epi = [=](int m, int n, float v) {
      const int b = m / 768, s = m - b * 768;
      const int h = n >> 6, d = n & 63;
      q[((size_t)((b * 12 + h) * 768 + s) << 6) + d] = (bf16_t)((v + bq[n]) * SCALE_Q);
    };
    gemm_core<64, 64, true, false>(smem, hid, 768, wT, 768, 768, m0, n0, epi);
  } else {
    const int m0 = blockIdx.x * 64, n0 = (blockIdx.y - 12) * 64;
    auto epi = [=](int m, int n, float v) {
      const float bias = (m < 768) ? bk[m] : bv[m - 768];
      ktvt[(size_t)m * 1536 + n] = (bf16_t)(v + bias);
    };
    gemm_core<64, 64, false, true>(smem, wT + 589824, 768, hid, 768, 768, m0, n0, epi);
  }
}

// Merged memory GEMMs (64x64 tiles).
//  y=0: kc[b][h*768+kout][d] = memk[h] @ k[b,h]
//  y=1: vct[b][d][h*768+kout] = (memv[h] @ v[b,h])^T
__global__ __launch_bounds__(256) void gemm_mem(const float* __restrict__ memk,
                                                const float* __restrict__ memv,
                                                const bf16_t* __restrict__ ktvt,
                                                bf16_t* __restrict__ kc,
                                                bf16_t* __restrict__ vct) {
  __shared__ __align__(16) char smem[(64 + 64) * 144];
  const int z = blockIdx.z, b = z / 12, h = z - (z / 12) * 12;
  if (blockIdx.y == 0) {
    const int m0 = blockIdx.x * 64;
    const float* A = memk + (size_t)h * 589824;
    const bf16_t* B = ktvt + (size_t)(h * 64) * 1536 + b * 768;
    bf16_t* outp = kc + (size_t)b * 589824 + (size_t)h * 768 * 64;
    auto epi = [=](int m, int n, float v) { outp[((size_t)m << 6) + n] = (bf16_t)v; };
    gemm_core<64, 64, true, false>(smem, A, 768, B, 1536, 768, m0, 0, epi);
  } else {
    const int n0 = blockIdx.x * 64;
    const bf16_t* A = ktvt + (size_t)(768 + h * 64) * 1536 + b * 768;
    const float* B = memv + (size_t)h * 589824;
    bf16_t* outp = vct + (size_t)b * 589824 + h * 768;
    auto epi = [=](int m, int n, float v) { outp[(size_t)m * 9216 + n] = (bf16_t)v; };
    gemm_core<64, 64, false, true>(smem, A, 1536, B, 768, 768, 0, n0, epi);
  }
}

// ---------------- flash attention, split-K, barrier-free -------------------
// Each wave owns 16 q-rows; B-fragments loaded directly from global (L1-hot);
// fixed-shift softmax: p = exp2(s + mask*log2e - 8); l reduced once at end.
__global__ __launch_bounds__(256, 4) void flash_attn_split(
    const bf16_t* __restrict__ q, const bf16_t* __restrict__ kc,
    const bf16_t* __restrict__ vct, const float* __restrict__ mask,
    float* __restrict__ part_acc, float* __restrict__ part_l) {
  const int qt = blockIdx.x, h = blockIdx.y;
  const int z = blockIdx.z, b = z >> 3, c = z & 7;
  const int tid = threadIdx.x;
  const int w = tid >> 6, lane = tid & 63, l15 = lane & 15, quad = lane >> 4;

  __shared__ __align__(16) bf16_t p_s[4][16 * 72];  // per-wave P [row][key], 144B rows
  bf16_t* psw = p_s[w];

  // Q fragments (A-operand, rows = wave's 16 q-rows), pre-scaled in gemm_q
  const bf16_t* qrow =
      q + ((size_t)((b * 12 + h) * 768 + qt * 64 + w * 16 + l15) << 6);
  const bf16x8 qa0 = *(const bf16x8*)(qrow + quad * 8);
  const bf16x8 qa1 = *(const bf16x8*)(qrow + 32 + quad * 8);

  const bf16_t* kcb = kc + (size_t)b * 589824;
  const bf16_t* vtb = vct + (size_t)b * 589824;
  const float* mkb = mask + b * 9216;

  const f32x4 fzero = {0.f, 0.f, 0.f, 0.f};
  float rsum[4] = {0.f, 0.f, 0.f, 0.f};  // lane-local partial of l
  f32x4 acc[4];
#pragma unroll
  for (int nt = 0; nt < 4; ++nt) acc[nt] = fzero;

#pragma unroll 2
  for (int t = 0; t < KCHUNK / 64; ++t) {
    const int k0 = c * KCHUNK + t * 64;

    // B-fragments straight from global: kc[key][d] and vct[d][key] are both
    // k-contiguous for their MFMA roles. 16 independent dwordx4 loads.
    bf16x8 kb0[4], kb1[4], vb0[4], vb1[4];
    float mk[4];
#pragma unroll
    for (int nt = 0; nt < 4; ++nt) {
      const bf16_t* kp = kcb + ((size_t)(k0 + nt * 16 + l15) << 6) + quad * 8;
      kb0[nt] = *(const bf16x8*)kp;
      kb1[nt] = *(const bf16x8*)(kp + 32);
      const bf16_t* vp = vtb + (size_t)(nt * 16 + l15) * 9216 + k0 + quad * 8;
      vb0[nt] = *(const bf16x8*)vp;
      vb1[nt] = *(const bf16x8*)(vp + 32);
      mk[nt] = fmaf(mkb[k0 + nt * 16 + l15], LOG2E, -SHIFT_C);
    }

    // S = Q.Kc^T (base-2 logits) -> P = exp2(S + mk), store P, lane-local sum
#pragma unroll
    for (int nt = 0; nt < 4; ++nt) {
      f32x4 zacc = fzero;
      zacc = MFMA16(qa0, kb0[nt], zacc);
      zacc = MFMA16(qa1, kb1[nt], zacc);
#pragma unroll
      for (int p = 0; p < 4; ++p) {
        const float pv = __builtin_amdgcn_exp2f(zacc[p] + mk[nt]);
        rsum[p] += pv;
        psw[(quad * 4 + p) * 72 + nt * 16 + l15] = (bf16_t)pv;
      }
    }

    // ctx += P.V  (A from per-wave P LDS; wave-internal dependency only)
    const bf16x8 pa0 = *(const bf16x8*)((char*)psw + l15 * 144 + quad * 16);
    const bf16x8 pa1 = *(const bf16x8*)((char*)psw + l15 * 144 + 64 + quad * 16);
#pragma unroll
    for (int nt = 0; nt < 4; ++nt) {
      acc[nt] = MFMA16(pa0, vb0[nt], acc[nt]);
      acc[nt] = MFMA16(pa1, vb1[nt], acc[nt]);
    }
  }

  // l[row] = sum over the 16 l15 lanes (rows live in quad groups)
#pragma unroll
  for (int p = 0; p < 4; ++p) {
    float v = rsum[p];
#pragma unroll
    for (int off = 1; off < 16; off <<= 1) v += __shfl_xor(v, off);
    rsum[p] = v;
  }

  const int pidx = ((b * 12 + h) * 12 + qt) * NSPLIT + c;
  float* pacc = part_acc + (size_t)pidx * 4096;
#pragma unroll
  for (int nt = 0; nt < 4; ++nt)
#pragma unroll
    for (int p = 0; p < 4; ++p)
      pacc[(w * 16 + quad * 4 + p) * 64 + nt * 16 + l15] = acc[nt][p];
  if (l15 == 0) {
#pragma unroll
    for (int p = 0; p < 4; ++p)
      part_l[(size_t)pidx * 64 + w * 16 + quad * 4 + p] = rsum[p];
  }
}

// ---------------- combine split-K partials, normalize, gate, write out -----
__global__ __launch_bounds__(1024) void flash_combine(
    const float* __restrict__ part_acc, const float* __restrict__ part_l,
    const float* __restrict__ gate, float* __restrict__ out) {
  const int qt = blockIdx.x, h = blockIdx.y, b = blockIdx.z;
  const int tid = threadIdx.x;
  const int row = tid >> 4, dseg = tid & 15;  // row 0..63, 4 d-elems per thread
  const int base = ((b * 12 + h) * 12 + qt) * NSPLIT;

  float L = 0.f;
#pragma unroll
  for (int ci = 0; ci < NSPLIT; ++ci) L += part_l[(size_t)(base + ci) * 64 + row];

  f32x4 accv = {0.f, 0.f, 0.f, 0.f};
#pragma unroll
  for (int ci = 0; ci < NSPLIT; ++ci) {
    const float4 v =
        *(const float4*)(part_acc + (size_t)(base + ci) * 4096 + row * 64 + dseg * 4);
    accv[0] += v.x;
    accv[1] += v.y;
    accv[2] += v.z;
    accv[3] += v.w;
  }
  const float g = 1.f / (1.f + expf(-gate[h]));
  const float sc = g / L;
  float4 o;
  o.x = accv[0] * sc;
  o.y = accv[1] * sc;
  o.z = accv[2] * sc;
  o.w = accv[3] * sc;
  *(float4*)(out + ((size_t)((b * 768 + qt * 64 + row) * 12 + h) << 6) + dseg * 4) = o;
}

extern "C" void kernel_launch(void* const* d_in, const int* in_sizes, int n_in,
                              void* d_out, int out_size, void* d_ws, size_t ws_size,
                              hipStream_t stream) {
  const float* hid  = (const float*)d_in[0];
  const float* mask = (const float*)d_in[1];
  const float* Wq   = (const float*)d_in[2];
  const float* bq   = (const float*)d_in[3];
  const float* Wk   = (const float*)d_in[4];
  const float* bk   = (const float*)d_in[5];
  const float* Wv   = (const float*)d_in[6];
  const float* bv   = (const float*)d_in[7];
  const float* gate = (const float*)d_in[8];
  const float* memk = (const float*)d_in[9];
  const float* memv = (const float*)d_in[10];
  float* out = (float*)d_out;

  // workspace layout (~53.7 MB total)
  char* ws = (char*)d_ws;
  bf16_t* wqkvT    = (bf16_t*)(ws);             // [2304][768] bf16
  bf16_t* qb       = (bf16_t*)(ws + 3538944);   // q [2][12][768][64] bf16
  bf16_t* ktvt     = (bf16_t*)(ws + 5898240);   // [1536][1536] bf16
  bf16_t* kcw      = (bf16_t*)(ws + 10616832);  // kc [2][9216][64] bf16
  bf16_t* vct      = (bf16_t*)(ws + 12976128);  // vc^T [2][64][9216] bf16
  float*  part_acc = (float*)(ws + 15335424);   // [2304][64][64] fp32
  float*  part_l   = (float*)(ws + 53084160);   // [2304][64] fp32

  transpose_cvt3<<<dim3(24, 24, 3), dim3(32, 8), 0, stream>>>(Wq, Wk, Wv, wqkvT);
  gemm_qkv<<<dim3(24, 36), 256, 0, stream>>>(hid, wqkvT, bq, bk, bv, qb, ktvt);
  gemm_mem<<<dim3(12, 2, 24), 256, 0, stream>>>(memk, memv, ktvt, kcw, vct);
  flash_attn_split<<<dim3(12, 12, 2 * NSPLIT), 256, 0, stream>>>(qb, kcw, vct, mask,
                                                                 part_acc, part_l);
  flash_combine<<<dim3(12, 12, 2), 1024, 0, stream>>>(part_acc, part_l, gate, out);
}

// Round 4
// 246.991 us; speedup vs baseline: 2.0072x; 2.0072x over previous
//
#include <hip/hip_runtime.h>
#include <hip/hip_bf16.h>

// B=2, S=768, H=768, NH=12, D=64, NKEY=9216. Output fp32 [B][S][NH][D].
// Round 4: flash rebuilt on 32x32x16 MFMA, 64 q-rows/wave, transposed-S trick:
// S^T = Kc.Q^T puts P^T in registers in a (K-permuted) B-operand layout; V
// A-frags use the SAME permutation via two 8B LDS reads -> zero P-LDS traffic,
// zero softmax shuffles. LDS staging shared per block + register prefetch.
// Mask folded multiplicatively: P = exp2(S) * w[k], w = exp2(mask*log2e - C).

typedef __bf16 bf16_t;
typedef __bf16 bf16x8 __attribute__((ext_vector_type(8)));
typedef float f32x4 __attribute__((ext_vector_type(4)));
typedef float f32x16 __attribute__((ext_vector_type(16)));
typedef unsigned long long u64;

#define MFMA16(a, b, c) __builtin_amdgcn_mfma_f32_16x16x32_bf16((a), (b), (c), 0, 0, 0)
#define MFMA32(a, b, c) __builtin_amdgcn_mfma_f32_32x32x16_bf16((a), (b), (c), 0, 0, 0)
#define LOG2E 1.44269504088896340736f
#define SCALE_Q 0.18033688011112042f /* (1/8) * log2(e) */
#define SHIFT_C 8.0f                 /* fixed softmax shift (base-2 units) */
#define NSPLIT 8
#define KCHUNK 1152 /* 9216/8, 18 iters of 64 */

// ---------------- transpose + convert: Wt[n][k] = (bf16)W[k][n], 768x768 ----
__global__ __launch_bounds__(256) void transpose_cvt3(const float* __restrict__ Wq,
                                                      const float* __restrict__ Wk,
                                                      const float* __restrict__ Wv,
                                                      bf16_t* __restrict__ Wt) {
  __shared__ float t[32][33];
  const float* W = (blockIdx.z == 0) ? Wq : (blockIdx.z == 1) ? Wk : Wv;
  bf16_t* o = Wt + (size_t)blockIdx.z * 589824;
  const int bx = blockIdx.x * 32;
  const int by = blockIdx.y * 32;
  const int tx = threadIdx.x, ty = threadIdx.y;
#pragma unroll
  for (int i = 0; i < 32; i += 8) t[ty + i][tx] = W[(bx + ty + i) * 768 + by + tx];
  __syncthreads();
#pragma unroll
  for (int i = 0; i < 32; i += 8)
    o[(by + ty + i) * 768 + bx + tx] = (bf16_t)t[tx][ty + i];
}

// ---------------- canonical C[M][N] = A[M][K] * B[N][K]^T, bf16 MFMA --------
__device__ __forceinline__ bf16x8 cvt8(const float* __restrict__ src) {
  const float4 a = *(const float4*)src;
  const float4 b = *(const float4*)(src + 4);
  bf16x8 o;
  o[0] = (bf16_t)a.x; o[1] = (bf16_t)a.y; o[2] = (bf16_t)a.z; o[3] = (bf16_t)a.w;
  o[4] = (bf16_t)b.x; o[5] = (bf16_t)b.y; o[6] = (bf16_t)b.z; o[7] = (bf16_t)b.w;
  return o;
}

template <int BM, int BN, bool AF32, bool BF32, typename EPI>
__device__ __forceinline__ void gemm_core(char* __restrict__ smem,
                                          const void* __restrict__ Ap, int lda,
                                          const void* __restrict__ Bp, int ldb,
                                          int K, int m0, int n0, EPI epi) {
  constexpr int MT = BM / 32;
  constexpr int NT = BN / 32;
  constexpr int ACH = BM * 8;
  constexpr int BCH = BN * 8;
  char* sA = smem;
  char* sB = smem + BM * 144;

  const int tid = threadIdx.x;
  const int lane = tid & 63;
  const int w = tid >> 6;
  const int l15 = lane & 15, quad = lane >> 4;
  const int wm = (w & 1) * (BM / 2);
  const int wn = (w >> 1) * (BN / 2);

  const f32x4 fzero = {0.f, 0.f, 0.f, 0.f};
  f32x4 acc[MT][NT];
#pragma unroll
  for (int i = 0; i < MT; ++i)
#pragma unroll
    for (int j = 0; j < NT; ++j) acc[i][j] = fzero;

  for (int kk = 0; kk < K; kk += 64) {
#pragma unroll
    for (int c = tid; c < ACH; c += 256) {
      const int r = c >> 3, ch = c & 7;
      if constexpr (AF32) {
        const float* s = (const float*)Ap + (size_t)(m0 + r) * lda + kk + ch * 8;
        *(bf16x8*)(sA + r * 144 + ch * 16) = cvt8(s);
      } else {
        const bf16_t* s = (const bf16_t*)Ap + (size_t)(m0 + r) * lda + kk + ch * 8;
        *(uint4*)(sA + r * 144 + ch * 16) = *(const uint4*)s;
      }
    }
#pragma unroll
    for (int c = tid; c < BCH; c += 256) {
      const int r = c >> 3, ch = c & 7;
      if constexpr (BF32) {
        const float* s = (const float*)Bp + (size_t)(n0 + r) * ldb + kk + ch * 8;
        *(bf16x8*)(sB + r * 144 + ch * 16) = cvt8(s);
      } else {
        const bf16_t* s = (const bf16_t*)Bp + (size_t)(n0 + r) * ldb + kk + ch * 8;
        *(uint4*)(sB + r * 144 + ch * 16) = *(const uint4*)s;
      }
    }
    __syncthreads();
#pragma unroll
    for (int ks = 0; ks < 2; ++ks) {
      bf16x8 af[MT], bfr[NT];
#pragma unroll
      for (int i = 0; i < MT; ++i)
        af[i] = *(const bf16x8*)(sA + (wm + i * 16 + l15) * 144 + ks * 64 + quad * 16);
#pragma unroll
      for (int j = 0; j < NT; ++j)
        bfr[j] = *(const bf16x8*)(sB + (wn + j * 16 + l15) * 144 + ks * 64 + quad * 16);
#pragma unroll
      for (int i = 0; i < MT; ++i)
#pragma unroll
        for (int j = 0; j < NT; ++j) acc[i][j] = MFMA16(af[i], bfr[j], acc[i][j]);
    }
    __syncthreads();
  }
#pragma unroll
  for (int i = 0; i < MT; ++i)
#pragma unroll
    for (int j = 0; j < NT; ++j)
#pragma unroll
      for (int p = 0; p < 4; ++p)
        epi(m0 + wm + i * 16 + quad * 4 + p, n0 + wn + j * 16 + l15, acc[i][j][p]);
}

// Merged QKV projections (64x64 tiles).
__global__ __launch_bounds__(256) void gemm_qkv(const float* __restrict__ hid,
                                                const bf16_t* __restrict__ wT,
                                                const float* __restrict__ bq,
                                                const float* __restrict__ bk,
                                                const float* __restrict__ bv,
                                                bf16_t* __restrict__ q,
                                                bf16_t* __restrict__ ktvt) {
  __shared__ __align__(16) char smem[(64 + 64) * 144];
  if (blockIdx.y < 12) {
    const int m0 = blockIdx.x * 64, n0 = blockIdx.y * 64;
    auto epi = [=](int m, int n, float v) {
      const int b = m / 768, s = m - b * 768;
      const int h = n >> 6, d = n & 63;
      q[((size_t)((b * 12 + h) * 768 + s) << 6) + d] = (bf16_t)((v + bq[n]) * SCALE_Q);
    };
    gemm_core<64, 64, true, false>(smem, hid, 768, wT, 768, 768, m0, n0, epi);
  } else {
    const int m0 = blockIdx.x * 64, n0 = (blockIdx.y - 12) * 64;
    auto epi = [=](int m, int n, float v) {
      const float bias = (m < 768) ? bk[m] : bv[m - 768];
      ktvt[(size_t)m * 1536 + n] = (bf16_t)(v + bias);
    };
    gemm_core<64, 64, false, true>(smem, wT + 589824, 768, hid, 768, 768, m0, n0, epi);
  }
}

// Merged memory GEMMs (64x64 tiles).
__global__ __launch_bounds__(256) void gemm_mem(const float* __restrict__ memk,
                                                const float* __restrict__ memv,
                                                const bf16_t* __restrict__ ktvt,
                                                bf16_t* __restrict__ kc,
                                                bf16_t* __restrict__ vct) {
  __shared__ __align__(16) char smem[(64 + 64) * 144];
  const int z = blockIdx.z, b = z / 12, h = z - (z / 12) * 12;
  if (blockIdx.y == 0) {
    const int m0 = blockIdx.x * 64;
    const float* A = memk + (size_t)h * 589824;
    const bf16_t* B = ktvt + (size_t)(h * 64) * 1536 + b * 768;
    bf16_t* outp = kc + (size_t)b * 589824 + (size_t)h * 768 * 64;
    auto epi = [=](int m, int n, float v) { outp[((size_t)m << 6) + n] = (bf16_t)v; };
    gemm_core<64, 64, true, false>(smem, A, 768, B, 1536, 768, m0, 0, epi);
  } else {
    const int n0 = blockIdx.x * 64;
    const bf16_t* A = ktvt + (size_t)(768 + h * 64) * 1536 + b * 768;
    const float* B = memv + (size_t)h * 589824;
    bf16_t* outp = vct + (size_t)b * 589824 + h * 768;
    auto epi = [=](int m, int n, float v) { outp[(size_t)m * 9216 + n] = (bf16_t)v; };
    gemm_core<64, 64, false, true>(smem, A, 1536, B, 768, 768, 0, n0, epi);
  }
}

// ---------------- flash attention, split-K, 32x32 MFMA, transposed-S -------
// Block: 4 waves x 64 q-rows = 256 q-rows. Per 64-key tile:
//   S^T[key][q] = Kc.Q^T  (A=Kc from LDS, B=Q in regs)
//   P^T = exp2(S^T) * w[key]  -> registers, packed bf16
//   O^T[d][q] += V^T.P^T      (A=V^T from LDS at permuted offsets, B=P^T regs)
// K-permutation contract (per 16-key MFMA step): slot(h5,j) <-> key
// 16*ks + 4*h5 + (j<4 ? j : 4+j). P^T C-layout supplies exactly this; V reads
// use two 8B LDS chunks at byte offsets 32*ks+8*h5 and +16 to match.
__global__ __launch_bounds__(256, 2) void flash_attn_split(
    const bf16_t* __restrict__ q, const bf16_t* __restrict__ kc,
    const bf16_t* __restrict__ vct, const float* __restrict__ mask,
    float* __restrict__ part_acc, float* __restrict__ part_l) {
  const int qt = blockIdx.x, h = blockIdx.y;
  const int z = blockIdx.z, b = z >> 3, c = z & 7;
  const int tid = threadIdx.x;
  const int w = tid >> 6, lane = tid & 63, l31 = lane & 31, h5 = lane >> 5;

  __shared__ __align__(16) bf16_t kc_s[64 * 72];  // [key][d], 144B rows
  __shared__ __align__(16) bf16_t vt_s[64 * 72];  // [d][key], 144B rows
  __shared__ float w_s[64];

  const bf16_t* kcb = kc + (size_t)b * 589824;
  const bf16_t* vtb = vct + (size_t)b * 589824;
  const float* mkb = mask + b * 9216;

  // Q B-frags, held for the whole kernel: qf[nb][kd] = Q[q0+nb*32+l31][16kd+8h5 ..+7]
  const int q0 = qt * 256 + w * 64;
  bf16x8 qf[2][4];
#pragma unroll
  for (int nb = 0; nb < 2; ++nb) {
    const bf16_t* qp = q + ((size_t)((b * 12 + h) * 768 + q0 + nb * 32 + l31) << 6) + h5 * 8;
#pragma unroll
    for (int kd = 0; kd < 4; ++kd) qf[nb][kd] = *(const bf16x8*)(qp + kd * 16);
  }

  f32x16 o[2][2];  // [nb][mb_d] O^T accumulators
#pragma unroll
  for (int nb = 0; nb < 2; ++nb)
#pragma unroll
    for (int md = 0; md < 2; ++md)
#pragma unroll
      for (int r = 0; r < 16; ++r) o[nb][md][r] = 0.f;
  float rsum[2] = {0.f, 0.f};

  // staging: thread owns 4 16B chunks (kc rows r8,32+r8; vt rows r8,32+r8)
  const int r8 = tid >> 3, ch8 = tid & 7;
  const int k0_0 = c * KCHUNK;
  uint4 pf0 = *(const uint4*)(kcb + ((size_t)(k0_0 + r8) << 6) + ch8 * 8);
  uint4 pf1 = *(const uint4*)(kcb + ((size_t)(k0_0 + 32 + r8) << 6) + ch8 * 8);
  uint4 pf2 = *(const uint4*)(vtb + (size_t)r8 * 9216 + k0_0 + ch8 * 8);
  uint4 pf3 = *(const uint4*)(vtb + (size_t)(32 + r8) * 9216 + k0_0 + ch8 * 8);
  float mraw = (tid < 64) ? mkb[k0_0 + tid] : 0.f;

  for (int t = 0; t < KCHUNK / 64; ++t) {
    *(uint4*)((char*)kc_s + r8 * 144 + ch8 * 16) = pf0;
    *(uint4*)((char*)kc_s + (32 + r8) * 144 + ch8 * 16) = pf1;
    *(uint4*)((char*)vt_s + r8 * 144 + ch8 * 16) = pf2;
    *(uint4*)((char*)vt_s + (32 + r8) * 144 + ch8 * 16) = pf3;
    if (tid < 64) w_s[tid] = exp2f(fmaf(mraw, LOG2E, -SHIFT_C));
    __syncthreads();

    if (t + 1 < KCHUNK / 64) {  // prefetch next tile behind compute
      const int k1 = c * KCHUNK + (t + 1) * 64;
      pf0 = *(const uint4*)(kcb + ((size_t)(k1 + r8) << 6) + ch8 * 8);
      pf1 = *(const uint4*)(kcb + ((size_t)(k1 + 32 + r8) << 6) + ch8 * 8);
      pf2 = *(const uint4*)(vtb + (size_t)r8 * 9216 + k1 + ch8 * 8);
      pf3 = *(const uint4*)(vtb + (size_t)(32 + r8) * 9216 + k1 + ch8 * 8);
      if (tid < 64) mraw = mkb[k1 + tid];
    }

#pragma unroll
    for (int mb = 0; mb < 2; ++mb) {  // 32-key block
      // Kc A-frags: ka[kd] = Kc[32mb+l31][16kd+8h5 ..+7]
      bf16x8 ka[4];
#pragma unroll
      for (int kd = 0; kd < 4; ++kd)
        ka[kd] = *(const bf16x8*)((char*)kc_s + (mb * 32 + l31) * 144 + kd * 32 + h5 * 16);
      // V A-frags at permuted key offsets: va[mb_d][tt]
      bf16x8 va[2][2];
#pragma unroll
      for (int md = 0; md < 2; ++md)
#pragma unroll
        for (int tt = 0; tt < 2; ++tt) {
          const char* vp =
              (char*)vt_s + (md * 32 + l31) * 144 + mb * 64 + tt * 32 + h5 * 8;
          union { u64 u[2]; bf16x8 v; } tmp;
          tmp.u[0] = *(const u64*)vp;
          tmp.u[1] = *(const u64*)(vp + 16);
          va[md][tt] = tmp.v;
        }
      // w values for this lane's 16 key slots (broadcast reads)
      float wv[16];
#pragma unroll
      for (int g = 0; g < 4; ++g) {
        const float4 t4 = *(const float4*)(w_s + mb * 32 + h5 * 4 + g * 8);
        wv[g * 4 + 0] = t4.x; wv[g * 4 + 1] = t4.y;
        wv[g * 4 + 2] = t4.z; wv[g * 4 + 3] = t4.w;
      }
#pragma unroll
      for (int nb = 0; nb < 2; ++nb) {
        f32x16 s;
#pragma unroll
        for (int r = 0; r < 16; ++r) s[r] = 0.f;
#pragma unroll
        for (int kd = 0; kd < 4; ++kd) s = MFMA32(ka[kd], qf[nb][kd], s);
        // P^T = exp2(S^T) * w ; lane's reg r holds (key=32mb+4h5+(r&3)+8(r>>2), q=l31)
        float pw[16];
#pragma unroll
        for (int r = 0; r < 16; ++r) {
          const float pv = __builtin_amdgcn_exp2f(s[r]) * wv[r];
          rsum[nb] += pv;
          pw[r] = pv;
        }
        bf16x8 pb0, pb1;
#pragma unroll
        for (int j = 0; j < 8; ++j) {
          pb0[j] = (bf16_t)pw[j];
          pb1[j] = (bf16_t)pw[8 + j];
        }
#pragma unroll
        for (int md = 0; md < 2; ++md) {
          o[nb][md] = MFMA32(va[md][0], pb0, o[nb][md]);
          o[nb][md] = MFMA32(va[md][1], pb1, o[nb][md]);
        }
      }
    }
    __syncthreads();
  }

  // finalize l per q-row (lane column q=l31; halves split across h5)
  const float l0 = rsum[0] + __shfl_xor(rsum[0], 32);
  const float l1 = rsum[1] + __shfl_xor(rsum[1], 32);

  const int pidx = ((b * 12 + h) * 3 + qt) * NSPLIT + c;
  float* pacc = part_acc + (size_t)pidx * 16384;
#pragma unroll
  for (int nb = 0; nb < 2; ++nb) {
    const int ql = w * 64 + nb * 32 + l31;
#pragma unroll
    for (int md = 0; md < 2; ++md)
#pragma unroll
      for (int g = 0; g < 4; ++g) {
        float4 v;
        v.x = o[nb][md][g * 4 + 0];
        v.y = o[nb][md][g * 4 + 1];
        v.z = o[nb][md][g * 4 + 2];
        v.w = o[nb][md][g * 4 + 3];
        *(float4*)(pacc + (size_t)ql * 64 + md * 32 + h5 * 4 + g * 8) = v;
      }
  }
  if (h5 == 0) {
    part_l[(size_t)pidx * 256 + w * 64 + l31] = l0;
    part_l[(size_t)pidx * 256 + w * 64 + 32 + l31] = l1;
  }
}

// ---------------- combine split-K partials, normalize, gate, write out -----
__global__ __launch_bounds__(1024) void flash_combine(
    const float* __restrict__ part_acc, const float* __restrict__ part_l,
    const float* __restrict__ gate, float* __restrict__ out) {
  const int qt = blockIdx.x, h = blockIdx.y, b = blockIdx.z;
  const int tid = threadIdx.x;
  const int row = tid >> 2, dseg = tid & 3;  // row 0..255, 16 d-elems each
  const int base = ((b * 12 + h) * 3 + qt) * NSPLIT;

  float L = 0.f;
#pragma unroll
  for (int ci = 0; ci < NSPLIT; ++ci) L += part_l[(size_t)(base + ci) * 256 + row];

  f32x4 accv[4] = {};
#pragma unroll
  for (int ci = 0; ci < NSPLIT; ++ci) {
    const float* p = part_acc + (size_t)(base + ci) * 16384 + row * 64 + dseg * 16;
#pragma unroll
    for (int j = 0; j < 4; ++j) {
      const float4 v = *(const float4*)(p + j * 4);
      accv[j][0] += v.x;
      accv[j][1] += v.y;
      accv[j][2] += v.z;
      accv[j][3] += v.w;
    }
  }
  const float g = 1.f / (1.f + expf(-gate[h]));
  const float sc = g / L;
  float* op = out + ((size_t)((b * 768 + qt * 256 + row) * 12 + h) << 6) + dseg * 16;
#pragma unroll
  for (int j = 0; j < 4; ++j) {
    float4 v;
    v.x = accv[j][0] * sc;
    v.y = accv[j][1] * sc;
    v.z = accv[j][2] * sc;
    v.w = accv[j][3] * sc;
    *(float4*)(op + j * 4) = v;
  }
}

extern "C" void kernel_launch(void* const* d_in, const int* in_sizes, int n_in,
                              void* d_out, int out_size, void* d_ws, size_t ws_size,
                              hipStream_t stream) {
  const float* hid  = (const float*)d_in[0];
  const float* mask = (const float*)d_in[1];
  const float* Wq   = (const float*)d_in[2];
  const float* bq   = (const float*)d_in[3];
  const float* Wk   = (const float*)d_in[4];
  const float* bk   = (const float*)d_in[5];
  const float* Wv   = (const float*)d_in[6];
  const float* bv   = (const float*)d_in[7];
  const float* gate = (const float*)d_in[8];
  const float* memk = (const float*)d_in[9];
  const float* memv = (const float*)d_in[10];
  float* out = (float*)d_out;

  // workspace layout (~53.7 MB total)
  char* ws = (char*)d_ws;
  bf16_t* wqkvT    = (bf16_t*)(ws);             // [2304][768] bf16
  bf16_t* qb       = (bf16_t*)(ws + 3538944);   // q [2][12][768][64] bf16
  bf16_t* ktvt     = (bf16_t*)(ws + 5898240);   // [1536][1536] bf16
  bf16_t* kcw      = (bf16_t*)(ws + 10616832);  // kc [2][9216][64] bf16
  bf16_t* vct      = (bf16_t*)(ws + 12976128);  // vc^T [2][64][9216] bf16
  float*  part_acc = (float*)(ws + 15335424);   // [576][256][64] fp32
  float*  part_l   = (float*)(ws + 53084160);   // [576][256] fp32

  transpose_cvt3<<<dim3(24, 24, 3), dim3(32, 8), 0, stream>>>(Wq, Wk, Wv, wqkvT);
  gemm_qkv<<<dim3(24, 36), 256, 0, stream>>>(hid, wqkvT, bq, bk, bv, qb, ktvt);
  gemm_mem<<<dim3(12, 2, 24), 256, 0, stream>>>(memk, memv, ktvt, kcw, vct);
  flash_attn_split<<<dim3(3, 12, 2 * NSPLIT), 256, 0, stream>>>(qb, kcw, vct, mask,
                                                                part_acc, part_l);
  flash_combine<<<dim3(3, 12, 2), 1024, 0, stream>>>(part_acc, part_l, gate, out);
}